// Round 1
// baseline (756.238 us; speedup 1.0000x reference)
//
#include <hip/hip_runtime.h>
#include <math.h>

#define BB 64
#define SS 4096
#define DD 512

// t[b,d] = sum_k topic[b,k] * W[k,d]
// grid: 64 b * 4 d-chunks = 256 blocks; block 256 threads.
// Each block computes 128 d-columns (32 float4 groups), k split into 8 strips.
__global__ __launch_bounds__(256) void tW_kernel(const float* __restrict__ topic,
                                                 const float* __restrict__ W,
                                                 float* __restrict__ t) {
    __shared__ float tp[DD];
    __shared__ float4 part[256];
    const int b      = blockIdx.x >> 2;
    const int dchunk = (blockIdx.x & 3) * 32;   // in float4 units (32 f4 = 128 floats)
    const int dg     = threadIdx.x & 31;        // float4 group within chunk
    const int strip  = threadIdx.x >> 5;        // 0..7, each owns 64 k
    for (int i = threadIdx.x; i < DD; i += 256) tp[i] = topic[b * DD + i];
    __syncthreads();
    const float4* W4 = (const float4*)W;        // row stride 128 float4
    float4 acc = {0.f, 0.f, 0.f, 0.f};
    const int k0 = strip * 64;
#pragma unroll 8
    for (int k = 0; k < 64; ++k) {
        const float s  = tp[k0 + k];
        const float4 w = W4[(size_t)(k0 + k) * 128 + dchunk + dg];
        acc.x += s * w.x; acc.y += s * w.y; acc.z += s * w.z; acc.w += s * w.w;
    }
    part[threadIdx.x] = acc;
    __syncthreads();
    if (threadIdx.x < 32) {
        float4 r = part[threadIdx.x];
#pragma unroll
        for (int st = 1; st < 8; ++st) {
            const float4 q = part[st * 32 + threadIdx.x];
            r.x += q.x; r.y += q.y; r.z += q.z; r.w += q.w;
        }
        ((float4*)(t + b * DD))[dchunk + dg] = r;
    }
}

// scores[b,s] = t[b] . seq[b,s] + bias
// v2: LDS-staged GEMV tile. Block = 256 threads handles 64 s-rows of one b.
// Tile streamed in 4 chunks of [64 rows x 128 floats] through LDS (padded
// stride 33 f4 -> uniform minimal 8 bank-cycles per b128 access, zero excess
// conflict). Thread (row=tid>>2, part=tid&3) keeps ONE private accumulator
// across all chunks -> only 2 shuffle ops per wave per tile (vs 48 before).
// Chunk c+1 loads issued into registers while chunk c computes.
#define ROWS 64
#define F4R  128          // float4 per seq row
#define LSTR 33           // LDS row stride in float4 (32 data + 1 pad)
__global__ __launch_bounds__(256) void scores_kernel(const float* __restrict__ t,
                                                     const float* __restrict__ seq,
                                                     const float* __restrict__ bias,
                                                     float* __restrict__ scores) {
    __shared__ float4 tile[ROWS * LSTR];   // 33.0 KB
    __shared__ float4 tvec4[DD / 4];       // 2 KB
    const int b   = blockIdx.y;
    const int s0  = blockIdx.x * ROWS;
    const int tid = threadIdx.x;
    const int row  = tid >> 2;             // 0..63
    const int part = tid & 3;              // 0..3, each owns 32 floats/chunk

    for (int i = tid; i < DD / 4; i += 256)
        tvec4[i] = ((const float4*)(t + (size_t)b * DD))[i];

    const float4* base = (const float4*)(seq + ((size_t)b * SS + s0) * DD);
    const int r0 = tid >> 5;               // staging row base, 0..7 step 8 per u
    const int g  = tid & 31;               // f4 within chunk-row

    float4 rv[8];
#pragma unroll
    for (int u = 0; u < 8; ++u)            // prologue: chunk 0 -> regs
        rv[u] = base[(size_t)(r0 + 8 * u) * F4R + g];

    float acc = 0.f;
#pragma unroll
    for (int c = 0; c < 4; ++c) {
        __syncthreads();                   // tile free (prev compute done)
#pragma unroll
        for (int u = 0; u < 8; ++u)
            tile[(r0 + 8 * u) * LSTR + g] = rv[u];
        __syncthreads();
        if (c < 3) {                       // issue next chunk under compute
#pragma unroll
            for (int u = 0; u < 8; ++u)
                rv[u] = base[(size_t)(r0 + 8 * u) * F4R + (c + 1) * 32 + g];
        }
#pragma unroll
        for (int k = 0; k < 8; ++k) {
            const float4 v  = tile[row * LSTR + part * 8 + k];
            const float4 tv = tvec4[c * 32 + part * 8 + k];
            acc += v.x * tv.x + v.y * tv.y + v.z * tv.z + v.w * tv.w;
        }
    }
    // 4-way reduce across parts (same wave: lanes tid^1, tid^2)
    acc += __shfl_xor(acc, 1, 64);
    acc += __shfl_xor(acc, 2, 64);
    if (part == 0)
        scores[(size_t)b * SS + s0 + row] = acc + bias[0];
}

// row softmax over S=4096, one block of 1024 threads per row (float4/thread)
__global__ __launch_bounds__(1024) void softmax_kernel(const float* __restrict__ scores,
                                                       float* __restrict__ out) {
    __shared__ float red[16];
    const int b   = blockIdx.x;
    const int tid = threadIdx.x;
    const int wave = tid >> 6, lane = tid & 63;

    const float4 v = ((const float4*)(scores + (size_t)b * SS))[tid];

    float m = fmaxf(fmaxf(v.x, v.y), fmaxf(v.z, v.w));
#pragma unroll
    for (int k = 32; k; k >>= 1) m = fmaxf(m, __shfl_xor(m, k, 64));
    if (lane == 0) red[wave] = m;
    __syncthreads();
    if (tid < 16) {
        float x = red[tid];
#pragma unroll
        for (int k = 8; k; k >>= 1) x = fmaxf(x, __shfl_xor(x, k, 16));
        if (tid == 0) red[0] = x;
    }
    __syncthreads();
    m = red[0];
    __syncthreads();

    float4 e;
    e.x = __expf(v.x - m); e.y = __expf(v.y - m);
    e.z = __expf(v.z - m); e.w = __expf(v.w - m);
    float s = e.x + e.y + e.z + e.w;
#pragma unroll
    for (int k = 32; k; k >>= 1) s += __shfl_xor(s, k, 64);
    if (lane == 0) red[wave] = s;
    __syncthreads();
    if (tid < 16) {
        float x = red[tid];
#pragma unroll
        for (int k = 8; k; k >>= 1) x += __shfl_xor(x, k, 16);
        if (tid == 0) red[0] = x;
    }
    __syncthreads();
    const float inv = 1.f / red[0];

    float4 o;
    o.x = e.x * inv; o.y = e.y * inv; o.z = e.z * inv; o.w = e.w * inv;
    ((float4*)(out + (size_t)b * SS))[tid] = o;
}

extern "C" void kernel_launch(void* const* d_in, const int* in_sizes, int n_in,
                              void* d_out, int out_size, void* d_ws, size_t ws_size,
                              hipStream_t stream) {
    const float* topic = (const float*)d_in[0];   // [B, D]
    const float* seq   = (const float*)d_in[1];   // [B, S, D]
    const float* W     = (const float*)d_in[2];   // [D, D]
    const float* bias  = (const float*)d_in[3];   // [1]
    float* out = (float*)d_out;                   // [B, S]

    float* t      = (float*)d_ws;                 // B*D floats
    float* scores = t + BB * DD;                  // B*S floats

    tW_kernel<<<dim3(BB * 4), 256, 0, stream>>>(topic, W, t);
    scores_kernel<<<dim3(SS / ROWS, BB), 256, 0, stream>>>(t, seq, bias, scores);
    softmax_kernel<<<dim3(BB), 1024, 0, stream>>>(scores, out);
}

// Round 2
// 680.231 us; speedup vs baseline: 1.1117x; 1.1117x over previous
//
#include <hip/hip_runtime.h>
#include <math.h>

#define BB 64
#define SS 4096
#define DD 512

// t[b,d] = sum_k topic[b,k] * W[k,d]
// grid: 64 b * 4 d-chunks = 256 blocks; block 256 threads.
__global__ __launch_bounds__(256) void tW_kernel(const float* __restrict__ topic,
                                                 const float* __restrict__ W,
                                                 float* __restrict__ t) {
    __shared__ float tp[DD];
    __shared__ float4 part[256];
    const int b      = blockIdx.x >> 2;
    const int dchunk = (blockIdx.x & 3) * 32;   // in float4 units (32 f4 = 128 floats)
    const int dg     = threadIdx.x & 31;        // float4 group within chunk
    const int strip  = threadIdx.x >> 5;        // 0..7, each owns 64 k
    for (int i = threadIdx.x; i < DD; i += 256) tp[i] = topic[b * DD + i];
    __syncthreads();
    const float4* W4 = (const float4*)W;        // row stride 128 float4
    float4 acc = {0.f, 0.f, 0.f, 0.f};
    const int k0 = strip * 64;
#pragma unroll 8
    for (int k = 0; k < 64; ++k) {
        const float s  = tp[k0 + k];
        const float4 w = W4[(size_t)(k0 + k) * 128 + dchunk + dg];
        acc.x += s * w.x; acc.y += s * w.y; acc.z += s * w.z; acc.w += s * w.w;
    }
    part[threadIdx.x] = acc;
    __syncthreads();
    if (threadIdx.x < 32) {
        float4 r = part[threadIdx.x];
#pragma unroll
        for (int st = 1; st < 8; ++st) {
            const float4 q = part[st * 32 + threadIdx.x];
            r.x += q.x; r.y += q.y; r.z += q.z; r.w += q.w;
        }
        ((float4*)(t + b * DD))[dchunk + dg] = r;
    }
}

// scores[b,s] = t[b] . seq[b,s] + bias
// v3: direct streaming (no LDS staging — seq has zero reuse), 16 rows per
// wave with per-lane private partials acc[16]. All loads are contiguous 1KB
// wave accesses. Wave-wide reduction of all 16 partials costs 17 shuffles
// total (fold 16->8->4->2->1 with masks 1,2,4,8; then xor 16,32), vs 96 in
// the old per-score butterfly. Chain depth 6, paid once per 16 rows.
__global__ __launch_bounds__(256) void scores_kernel(const float* __restrict__ t,
                                                     const float* __restrict__ seq,
                                                     const float* __restrict__ bias,
                                                     float* __restrict__ scores) {
    const int b    = blockIdx.y;
    const int wave = threadIdx.x >> 6;
    const int lane = threadIdx.x & 63;
    const int s0   = blockIdx.x * 64 + wave * 16;   // 16 rows per wave

    const float4* trow = (const float4*)(t + (size_t)b * DD);
    const float4 ta = trow[lane];
    const float4 tb = trow[lane + 64];

    const float4* base = (const float4*)(seq + ((size_t)b * SS + s0) * DD);

    float acc[16];
#pragma unroll
    for (int r = 0; r < 16; ++r) {
        const float4* p = base + (size_t)r * 128;
        const float4 a = p[lane];
        const float4 c = p[lane + 64];
        acc[r] = a.x * ta.x + a.y * ta.y + a.z * ta.z + a.w * ta.w
               + c.x * tb.x + c.y * tb.y + c.z * tb.z + c.w * tb.w;
    }

    // Fold 16 values -> 1 across the wave. Step with mask m, count N:
    //   s = (lane&m) ? acc[i] : acc[i+N/2];  y = shfl_xor(s, m);
    //   acc[i] = ((lane&m) ? acc[i+N/2] : acc[i]) + y;
    // Removed row-bit = (lane&m)!=0, so final row = bitrev4(lane&15).
#pragma unroll
    for (int i = 0; i < 8; ++i) {
        const float s = (lane & 1) ? acc[i] : acc[i + 8];
        const float y = __shfl_xor(s, 1, 64);
        acc[i] = ((lane & 1) ? acc[i + 8] : acc[i]) + y;
    }
#pragma unroll
    for (int i = 0; i < 4; ++i) {
        const float s = (lane & 2) ? acc[i] : acc[i + 4];
        const float y = __shfl_xor(s, 2, 64);
        acc[i] = ((lane & 2) ? acc[i + 4] : acc[i]) + y;
    }
#pragma unroll
    for (int i = 0; i < 2; ++i) {
        const float s = (lane & 4) ? acc[i] : acc[i + 2];
        const float y = __shfl_xor(s, 4, 64);
        acc[i] = ((lane & 4) ? acc[i + 2] : acc[i]) + y;
    }
    {
        const float s = (lane & 8) ? acc[0] : acc[1];
        const float y = __shfl_xor(s, 8, 64);
        acc[0] = ((lane & 8) ? acc[1] : acc[0]) + y;
    }
    acc[0] += __shfl_xor(acc[0], 16, 64);
    acc[0] += __shfl_xor(acc[0], 32, 64);

    if (lane < 16) {
        const int r = ((lane & 1) << 3) | ((lane & 2) << 1)
                    | ((lane & 4) >> 1) | ((lane & 8) >> 3);
        scores[(size_t)b * SS + s0 + r] = acc[0] + bias[0];
    }
}

// row softmax over S=4096, one block of 1024 threads per row (float4/thread)
__global__ __launch_bounds__(1024) void softmax_kernel(const float* __restrict__ scores,
                                                       float* __restrict__ out) {
    __shared__ float red[16];
    const int b   = blockIdx.x;
    const int tid = threadIdx.x;
    const int wave = tid >> 6, lane = tid & 63;

    const float4 v = ((const float4*)(scores + (size_t)b * SS))[tid];

    float m = fmaxf(fmaxf(v.x, v.y), fmaxf(v.z, v.w));
#pragma unroll
    for (int k = 32; k; k >>= 1) m = fmaxf(m, __shfl_xor(m, k, 64));
    if (lane == 0) red[wave] = m;
    __syncthreads();
    if (tid < 16) {
        float x = red[tid];
#pragma unroll
        for (int k = 8; k; k >>= 1) x = fmaxf(x, __shfl_xor(x, k, 16));
        if (tid == 0) red[0] = x;
    }
    __syncthreads();
    m = red[0];
    __syncthreads();

    float4 e;
    e.x = __expf(v.x - m); e.y = __expf(v.y - m);
    e.z = __expf(v.z - m); e.w = __expf(v.w - m);
    float s = e.x + e.y + e.z + e.w;
#pragma unroll
    for (int k = 32; k; k >>= 1) s += __shfl_xor(s, k, 64);
    if (lane == 0) red[wave] = s;
    __syncthreads();
    if (tid < 16) {
        float x = red[tid];
#pragma unroll
        for (int k = 8; k; k >>= 1) x += __shfl_xor(x, k, 16);
        if (tid == 0) red[0] = x;
    }
    __syncthreads();
    const float inv = 1.f / red[0];

    float4 o;
    o.x = e.x * inv; o.y = e.y * inv; o.z = e.z * inv; o.w = e.w * inv;
    ((float4*)(out + (size_t)b * SS))[tid] = o;
}

extern "C" void kernel_launch(void* const* d_in, const int* in_sizes, int n_in,
                              void* d_out, int out_size, void* d_ws, size_t ws_size,
                              hipStream_t stream) {
    const float* topic = (const float*)d_in[0];   // [B, D]
    const float* seq   = (const float*)d_in[1];   // [B, S, D]
    const float* W     = (const float*)d_in[2];   // [D, D]
    const float* bias  = (const float*)d_in[3];   // [1]
    float* out = (float*)d_out;                   // [B, S]

    float* t      = (float*)d_ws;                 // B*D floats
    float* scores = t + BB * DD;                  // B*S floats

    tW_kernel<<<dim3(BB * 4), 256, 0, stream>>>(topic, W, t);
    scores_kernel<<<dim3(SS / 64, BB), 256, 0, stream>>>(t, seq, bias, scores);
    softmax_kernel<<<dim3(BB), 1024, 0, stream>>>(scores, out);
}